// Round 10
// baseline (279.293 us; speedup 1.0000x reference)
//
#include <hip/hip_runtime.h>
#include <hip/hip_bf16.h>
#include <cstdint>

typedef __bf16 bf16;
typedef __bf16 bf16x4 __attribute__((ext_vector_type(4)));
typedef __bf16 bf16x8 __attribute__((ext_vector_type(8)));
typedef float f32x4 __attribute__((ext_vector_type(4)));

#define GK 768   // inner K for both GEMMs
#define LN_EPS 1e-5f
#define NORM_EPS 1e-12f

// ---------------- async global->LDS helper ----------------
__device__ __forceinline__ void gl_lds16(const void* g, void* l) {
  __builtin_amdgcn_global_load_lds(
      (__attribute__((address_space(1))) uint32_t*)(uintptr_t)g,
      (__attribute__((address_space(3))) uint32_t*)(uintptr_t)l,
      16, 0, 0);
}

// ---------------- block reduce (2 values, 3 waves / 192 threads) ----------------
__device__ __forceinline__ void blockReduce2w3(float& s, float& ss, float* sm) {
  #pragma unroll
  for (int o = 32; o > 0; o >>= 1) {
    s  += __shfl_down(s, o, 64);
    ss += __shfl_down(ss, o, 64);
  }
  int wave = threadIdx.x >> 6, lane = threadIdx.x & 63;
  if (lane == 0) { sm[wave] = s; sm[3 + wave] = ss; }
  __syncthreads();
  s  = sm[0] + sm[1] + sm[2];
  ss = sm[3] + sm[4] + sm[5];
  __syncthreads();
}

// ---------------- 0: fp32 weights -> MFMA-frag-packed bf16 ----------------
// w [768][Ncols] fp32 -> pack, t-major within panel:
//   f = ((cb*2+wn)*12 + t)*8 + (j*2 + ks)       [matches GEMM's bp + t*4096]
// Content: pack[f][lane=(llo,lhi)][e] = w[t*64+ks*32+lhi*8+e][cb*128+wn*64+j*16+llo].
__global__ __launch_bounds__(256) void transpose_cvt_pack(const float* __restrict__ w,
                                                          bf16* __restrict__ pack,
                                                          int Ncols) {
  __shared__ float tile[32][33];
  int tx = threadIdx.x & 31, ty = threadIdx.x >> 5;   // 32 x 8
  int c0 = blockIdx.x * 32, k0 = blockIdx.y * 32;
  #pragma unroll
  for (int i = 0; i < 32; i += 8)
    tile[ty + i][tx] = w[(size_t)(k0 + ty + i) * Ncols + (c0 + tx)];
  __syncthreads();
  int tid = threadIdx.x;
  if (tid < 128) {
    int fi = tid >> 6, lane = tid & 63;
    int llo = lane & 15, lhi = lane >> 4;
    int cb = c0 >> 7, wn = (c0 >> 6) & 1, j = ((c0 & 63) >> 4) + fi;
    int t = k0 >> 6, ks = (k0 >> 5) & 1;
    int f = ((cb * 2 + wn) * 12 + t) * 8 + (j * 2 + ks);   // t-major (bug fix)
    bf16x8 o;
    #pragma unroll
    for (int e = 0; e < 8; ++e) o[e] = (bf16)tile[lhi * 8 + e][fi * 16 + llo];
    *(bf16x8*)(pack + (size_t)f * 512 + lane * 8) = o;
  }
}

// ---------------- 1: input LayerNorm -> bf16 (192 threads) ----------
__global__ __launch_bounds__(192) void ln_in_kernel(const float* __restrict__ x,
                                                    const float* __restrict__ g,
                                                    const float* __restrict__ b,
                                                    bf16* __restrict__ h) {
  __shared__ float sm[6];
  int row = blockIdx.x, t = threadIdx.x;
  const float* xr = x + (size_t)row * 768;
  float4 v = ((const float4*)xr)[t];
  float s  = v.x + v.y + v.z + v.w;
  float ss = v.x * v.x + v.y * v.y + v.z * v.z + v.w * v.w;
  blockReduce2w3(s, ss, sm);
  float mu  = s * (1.0f / 768.0f);
  float inv = rsqrtf(ss * (1.0f / 768.0f) - mu * mu + LN_EPS);
  float4 gg = ((const float4*)g)[t];
  float4 bb = ((const float4*)b)[t];
  bf16x4 o;
  o[0] = (bf16)((v.x - mu) * inv * gg.x + bb.x);
  o[1] = (bf16)((v.y - mu) * inv * gg.y + bb.y);
  o[2] = (bf16)((v.z - mu) * inv * gg.z + bb.z);
  o[3] = (bf16)((v.w - mu) * inv * gg.w + bb.w);
  ((bf16x4*)(h + (size_t)row * 768))[t] = o;
}

// ================= 128x128 bf16 GEMM: A via swizzled LDS, B direct L2->reg ==
// 256 threads = 4 waves (2m x 2n), wave = 64x64. BK=64 -> 12 K-tiles.
// LDS 32 KiB (A only, 2 bufs). B frags from frag-packed global (coalesced 1KB
// loads, L2-resident), double-buffered in registers (bfA/bfB).
// vmcnt ledger (per wave, per iter): issue RDALL, BLOAD(t+1) [8], MFMA, BAR,
// STAGE(t+2) [4]. At iter start VMC(4) leaves newest stage in flight, drains
// bload(t) and stage(t). Tail iter uses VMC(0). Ledger re-audited round 9.
// T2 swizzle on A: XOR byte-bits 4-6 with row-bits 0-2 (involution, both sides).

#define SWZ(x) ((x) ^ ((((x) >> 7) & 7) << 4))

#define BAR __builtin_amdgcn_s_barrier()
#define VMC(n) asm volatile("s_waitcnt vmcnt(" #n ")" ::: "memory")
#define PRIO1 __builtin_amdgcn_s_setprio(1)
#define PRIO0 __builtin_amdgcn_s_setprio(0)

#define LDA1(base, i, ks) \
  af[i][ks] = *(const bf16x8*)((base) + SWZ((wm * 64 + (i) * 16 + llo) * 128 + (ks) * 64 + lhi * 16))
#define RDALL_A(Ab) do { \
  LDA1(Ab, 0, 0); LDA1(Ab, 1, 0); LDA1(Ab, 2, 0); LDA1(Ab, 3, 0); \
  LDA1(Ab, 0, 1); LDA1(Ab, 1, 1); LDA1(Ab, 2, 1); LDA1(Ab, 3, 1); } while (0)

// B frag loads: P points at this wave's panel base for tile t (elements)
#define BLOADP(S, P) do { \
  S[0][0] = *(const bf16x8*)((P) + 0);    S[0][1] = *(const bf16x8*)((P) + 512); \
  S[1][0] = *(const bf16x8*)((P) + 1024); S[1][1] = *(const bf16x8*)((P) + 1536); \
  S[2][0] = *(const bf16x8*)((P) + 2048); S[2][1] = *(const bf16x8*)((P) + 2560); \
  S[3][0] = *(const bf16x8*)((P) + 3072); S[3][1] = *(const bf16x8*)((P) + 3584); } while (0)

#define MF1S(S, m, n, ks) \
  acc[m][n] = __builtin_amdgcn_mfma_f32_16x16x32_bf16(af[m][ks], S[n][ks], acc[m][n], 0, 0, 0)
#define MFALLS(S) do { PRIO1; \
  MF1S(S,0,0,0); MF1S(S,0,1,0); MF1S(S,0,2,0); MF1S(S,0,3,0); \
  MF1S(S,1,0,0); MF1S(S,1,1,0); MF1S(S,1,2,0); MF1S(S,1,3,0); \
  MF1S(S,2,0,0); MF1S(S,2,1,0); MF1S(S,2,2,0); MF1S(S,2,3,0); \
  MF1S(S,3,0,0); MF1S(S,3,1,0); MF1S(S,3,2,0); MF1S(S,3,3,0); \
  MF1S(S,0,0,1); MF1S(S,0,1,1); MF1S(S,0,2,1); MF1S(S,0,3,1); \
  MF1S(S,1,0,1); MF1S(S,1,1,1); MF1S(S,1,2,1); MF1S(S,1,3,1); \
  MF1S(S,2,0,1); MF1S(S,2,1,1); MF1S(S,2,2,1); MF1S(S,2,3,1); \
  MF1S(S,3,0,1); MF1S(S,3,1,1); MF1S(S,3,2,1); MF1S(S,3,3,1); \
  PRIO0; } while (0)

#define STA2(b, q, t) gl_lds16(A + srcA[q] + (t) * 64, &As_[b][(q) * 2048 + wave * 512])
#define STAGE(b, t) do { STA2(b, 0, t); STA2(b, 1, t); STA2(b, 2, t); STA2(b, 3, t); } while (0)

template <bool OUT_BF16>
__global__ __launch_bounds__(256, 2) void gemm128b(const bf16* __restrict__ A,
                                                   const bf16* __restrict__ Bp,
                                                   void* __restrict__ Cv,
                                                   int Nn, int NBN) {
  __shared__ __align__(16) bf16 As_[2][8192];   // 16KB per buf, A only
  const int tid = threadIdx.x;
  const int wave = tid >> 6, lane = tid & 63;
  const int llo = lane & 15, lhi = lane >> 4;
  const int wm = wave >> 1, wn = wave & 1;

  const int nwg = gridDim.x, bid = blockIdx.x;
  const int wg = (bid & 7) * (nwg >> 3) + (bid >> 3);
  const int rb = wg / NBN, cb = wg - rb * NBN;
  const int brow = rb * 128, bcol = cb * 128;

  // A stage source offsets (involution pre-swizzle)
  uint32_t srcA[4];
  #pragma unroll
  for (int q = 0; q < 4; ++q) {
    int d = q * 4096 + tid * 16;
    int a = SWZ(d);
    int r = a >> 7, c = (a & 127) >> 1;
    srcA[q] = (uint32_t)(brow + r) * GK + c;
  }

  // per-wave B panel (96KB = 12 tiles x 4KB), per-lane 16B slot
  const bf16* bp = Bp + (size_t)(cb * 2 + wn) * 49152 + lane * 8;

  f32x4 acc[4][4];
  #pragma unroll
  for (int m = 0; m < 4; ++m)
    #pragma unroll
    for (int n = 0; n < 4; ++n) acc[m][n] = (f32x4){0.f, 0.f, 0.f, 0.f};

  bf16x8 af[4][2], bfA[4][2], bfB[4][2];
  const char* As0 = (const char*)&As_[0][0];
  const char* As1 = (const char*)&As_[1][0];

  // prologue: B(t0) first, then A stages (order matters for vmcnt ledger)
  BLOADP(bfA, bp);
  STAGE(0, 0);
  STAGE(1, 1);

  for (int jp = 0; jp < 5; ++jp) {
    const int t = 2 * jp;
    // even tile t (buf0, bfA); prefetch B(t+1)->bfB, stage A(t+2)->buf0
    VMC(4);
    BAR;
    RDALL_A(As0);
    BLOADP(bfB, bp + 4096);
    MFALLS(bfA);
    BAR;
    STAGE(0, t + 2);
    // odd tile t+1 (buf1, bfB); prefetch B(t+2)->bfA, stage A(t+3)->buf1
    VMC(4);
    BAR;
    RDALL_A(As1);
    BLOADP(bfA, bp + 8192);
    MFALLS(bfB);
    BAR;
    STAGE(1, t + 3);
    bp += 8192;
  }
  // t=10 (buf0, bfA); prefetch B(11); no stage
  VMC(4);
  BAR;
  RDALL_A(As0);
  BLOADP(bfB, bp + 4096);
  MFALLS(bfA);
  BAR;
  // t=11 (buf1, bfB)
  VMC(0);
  BAR;
  RDALL_A(As1);
  MFALLS(bfB);

  // epilogue: C write
  #pragma unroll
  for (int m = 0; m < 4; ++m) {
    #pragma unroll
    for (int n = 0; n < 4; ++n) {
      int row = brow + wm * 64 + m * 16 + lhi * 4;
      int col = bcol + wn * 64 + n * 16 + llo;
      #pragma unroll
      for (int r2 = 0; r2 < 4; ++r2) {
        if (OUT_BF16)
          ((bf16*)Cv)[(size_t)(row + r2) * Nn + col] = (bf16)acc[m][n][r2];
        else
          ((float*)Cv)[(size_t)(row + r2) * Nn + col] = acc[m][n][r2];
      }
    }
  }
}

// ---------------- 3a: kv partial sums, k-norm computed inline ----------------
__global__ __launch_bounds__(256) void kv_partial(const bf16* __restrict__ qkv,
                                                  float* __restrict__ kvp) {
  __shared__ float sm[4][768];
  int b = blockIdx.x >> 5, chunk = blockIdx.x & 31;
  int wave = threadIdx.x >> 6, lane = threadIdx.x & 63;
  const bf16* base = qkv + ((size_t)(b * 4096 + chunk * 128 + wave * 32)) * 2304;
  float acc[3][4] = {};
  for (int i = 0; i < 32; ++i) {
    const bf16* kr = base + (size_t)i * 2304 + 768;
    const bf16* vr = kr + 768;
    bf16x4 k4[3], v4[3];
    #pragma unroll
    for (int c = 0; c < 3; ++c) {
      k4[c] = *(const bf16x4*)(kr + c * 256 + lane * 4);
      v4[c] = *(const bf16x4*)(vr + c * 256 + lane * 4);
    }
    float ssk = 0.f;
    #pragma unroll
    for (int c = 0; c < 3; ++c)
      #pragma unroll
      for (int j = 0; j < 4; ++j) { float kf = (float)k4[c][j]; ssk += kf * kf; }
    #pragma unroll
    for (int off = 32; off > 0; off >>= 1) ssk += __shfl_xor(ssk, off, 64);
    float wi = 1.0f / fmaxf(sqrtf(ssk), NORM_EPS);
    #pragma unroll
    for (int c = 0; c < 3; ++c)
      #pragma unroll
      for (int j = 0; j < 4; ++j)
        acc[c][j] += (float)k4[c][j] * (float)v4[c][j] * wi;
  }
  #pragma unroll
  for (int c = 0; c < 3; ++c)
    #pragma unroll
    for (int j = 0; j < 4; ++j)
      sm[wave][c * 256 + lane * 4 + j] = acc[c][j];
  __syncthreads();
  int t = threadIdx.x;
  #pragma unroll
  for (int c = 0; c < 3; ++c) {
    int e = c * 256 + t;
    kvp[(size_t)blockIdx.x * 768 + e] = sm[0][e] + sm[1][e] + sm[2][e] + sm[3][e];
  }
}

// ---------------- 3b: reduce 32 partials -> kv[8][768] ----------------
__global__ __launch_bounds__(256) void kv_reduce(const float* __restrict__ kvp,
                                                 float* __restrict__ kv) {
  int i = blockIdx.x * 256 + threadIdx.x;
  int b = i / 768, e = i - b * 768;
  float s = 0.f;
  #pragma unroll
  for (int c = 0; c < 32; ++c) s += kvp[(size_t)(b * 32 + c) * 768 + e];
  kv[i] = s;
}

// ---------------- 4: attn = phi_q * kv (q-norm inline), LN over E -> bf16 ----
__global__ __launch_bounds__(192) void attn_ln_kernel(const bf16* __restrict__ qkv,
                                                      const float* __restrict__ kv,
                                                      const float* __restrict__ g,
                                                      const float* __restrict__ b,
                                                      bf16* __restrict__ a) {
  __shared__ float sm[6];
  int row = blockIdx.x, t = threadIdx.x;
  int bt = row >> 12;
  const bf16* qr = qkv + (size_t)row * 2304;
  bf16x4 q4 = ((const bf16x4*)qr)[t];
  float q0 = (float)q4[0], q1 = (float)q4[1], q2 = (float)q4[2], q3 = (float)q4[3];
  float sq = q0 * q0 + q1 * q1 + q2 * q2 + q3 * q3, dummy = 0.f;
  blockReduce2w3(sq, dummy, sm);
  float iq = 1.0f / fmaxf(sqrtf(sq), NORM_EPS);
  float4 kv4 = ((const float4*)(kv + bt * 768))[t];
  float4 av;
  av.x = q0 * iq * kv4.x;
  av.y = q1 * iq * kv4.y;
  av.z = q2 * iq * kv4.z;
  av.w = q3 * iq * kv4.w;
  float s  = av.x + av.y + av.z + av.w;
  float ss = av.x * av.x + av.y * av.y + av.z * av.z + av.w * av.w;
  blockReduce2w3(s, ss, sm);
  float mu  = s * (1.0f / 768.0f);
  float inv = rsqrtf(ss * (1.0f / 768.0f) - mu * mu + LN_EPS);
  float4 gg = ((const float4*)g)[t];
  float4 bb = ((const float4*)b)[t];
  bf16x4 o;
  o[0] = (bf16)((av.x - mu) * inv * gg.x + bb.x);
  o[1] = (bf16)((av.y - mu) * inv * gg.y + bb.y);
  o[2] = (bf16)((av.z - mu) * inv * gg.z + bb.z);
  o[3] = (bf16)((av.w - mu) * inv * gg.w + bb.w);
  ((bf16x4*)(a + (size_t)row * 768))[t] = o;
}

// ---------------- launcher ----------------
extern "C" void kernel_launch(void* const* d_in, const int* in_sizes, int n_in,
                              void* d_out, int out_size, void* d_ws, size_t ws_size,
                              hipStream_t stream) {
  const float* x      = (const float*)d_in[0];
  const float* w_qkv  = (const float*)d_in[1];
  const float* w_proj = (const float*)d_in[2];
  const float* g_in   = (const float*)d_in[3];
  const float* b_in   = (const float*)d_in[4];
  const float* g_out  = (const float*)d_in[5];
  const float* b_out  = (const float*)d_in[6];

  char* ws = (char*)d_ws;
  bf16*  bqp    = (bf16*)(ws);                              // qkv B-pack  [3538944 B]
  bf16*  bpp    = (bf16*)(ws + 3538944);                    // proj B-pack [1179648 B]
  bf16*  h      = (bf16*)(ws + 4718592);                    // [32768][768] bf16 (reused as 'a')
  bf16*  qkv    = (bf16*)(ws + 55050240);                   // [32768][2304] bf16
  float* kvp    = (float*)(ws + 206045184);                 // [8*32][768]
  float* kv     = (float*)(ws + 206831616);                 // [8][768]

  transpose_cvt_pack<<<dim3(2304 / 32, 768 / 32), 256, 0, stream>>>(w_qkv, bqp, 2304);
  transpose_cvt_pack<<<dim3(768 / 32, 768 / 32), 256, 0, stream>>>(w_proj, bpp, 768);
  ln_in_kernel<<<32768, 192, 0, stream>>>(x, g_in, b_in, h);
  gemm128b<true><<<256 * 18, 256, 0, stream>>>(h, bqp, (void*)qkv, 2304, 18);
  kv_partial<<<256, 256, 0, stream>>>(qkv, kvp);
  kv_reduce<<<24, 256, 0, stream>>>(kvp, kv);
  attn_ln_kernel<<<32768, 192, 0, stream>>>(qkv, kv, g_out, b_out, h);
  gemm128b<false><<<256 * 6, 256, 0, stream>>>(h, bpp, d_out, 768, 6);
}

// Round 11
// 249.489 us; speedup vs baseline: 1.1195x; 1.1195x over previous
//
#include <hip/hip_runtime.h>
#include <hip/hip_bf16.h>
#include <cstdint>

typedef __bf16 bf16;
typedef __bf16 bf16x4 __attribute__((ext_vector_type(4)));
typedef __bf16 bf16x8 __attribute__((ext_vector_type(8)));
typedef float f32x4 __attribute__((ext_vector_type(4)));

#define GK 768   // inner K for both GEMMs
#define LN_EPS 1e-5f
#define NORM_EPS 1e-12f

// ---------------- async global->LDS helper ----------------
__device__ __forceinline__ void gl_lds16(const void* g, void* l) {
  __builtin_amdgcn_global_load_lds(
      (__attribute__((address_space(1))) uint32_t*)(uintptr_t)g,
      (__attribute__((address_space(3))) uint32_t*)(uintptr_t)l,
      16, 0, 0);
}

// ---------------- 0: tiled transpose + fp32->bf16 ----------------
__global__ __launch_bounds__(256) void transpose_cvt(const float* __restrict__ w,
                                                     bf16* __restrict__ wt,
                                                     int R, int Ncols) {
  __shared__ float tile[32][33];
  int tx = threadIdx.x & 31, ty = threadIdx.x >> 5;
  int c0 = blockIdx.x * 32, r0 = blockIdx.y * 32;
  #pragma unroll
  for (int i = 0; i < 32; i += 8)
    tile[ty + i][tx] = w[(size_t)(r0 + ty + i) * Ncols + (c0 + tx)];
  __syncthreads();
  #pragma unroll
  for (int i = 0; i < 32; i += 8)
    wt[(size_t)(c0 + ty + i) * R + (r0 + tx)] = (bf16)tile[tx][ty + i];
}

// ---------------- 1: input LayerNorm -> bf16, wave-per-row ----------
// 256 thr = 4 waves, each wave owns one row (768 fp32 = 12 floats/lane).
__global__ __launch_bounds__(256) void ln_in_kernel(const float* __restrict__ x,
                                                    const float* __restrict__ g,
                                                    const float* __restrict__ b,
                                                    bf16* __restrict__ h) {
  int wave = threadIdx.x >> 6, lane = threadIdx.x & 63;
  int row = blockIdx.x * 4 + wave;
  const float* xr = x + (size_t)row * 768;
  float4 v0 = ((const float4*)xr)[lane];
  float4 v1 = ((const float4*)xr)[lane + 64];
  float4 v2 = ((const float4*)xr)[lane + 128];
  float s  = v0.x + v0.y + v0.z + v0.w + v1.x + v1.y + v1.z + v1.w
           + v2.x + v2.y + v2.z + v2.w;
  float ss = v0.x*v0.x + v0.y*v0.y + v0.z*v0.z + v0.w*v0.w
           + v1.x*v1.x + v1.y*v1.y + v1.z*v1.z + v1.w*v1.w
           + v2.x*v2.x + v2.y*v2.y + v2.z*v2.z + v2.w*v2.w;
  #pragma unroll
  for (int o = 32; o > 0; o >>= 1) {
    s  += __shfl_xor(s, o, 64);
    ss += __shfl_xor(ss, o, 64);
  }
  float mu  = s * (1.0f / 768.0f);
  float inv = rsqrtf(ss * (1.0f / 768.0f) - mu * mu + LN_EPS);
  bf16* hr = h + (size_t)row * 768;
  #pragma unroll
  for (int c = 0; c < 3; ++c) {
    float4 v = c == 0 ? v0 : (c == 1 ? v1 : v2);
    float4 gg = ((const float4*)g)[lane + c * 64];
    float4 bb = ((const float4*)b)[lane + c * 64];
    bf16x4 o;
    o[0] = (bf16)((v.x - mu) * inv * gg.x + bb.x);
    o[1] = (bf16)((v.y - mu) * inv * gg.y + bb.y);
    o[2] = (bf16)((v.z - mu) * inv * gg.z + bb.z);
    o[3] = (bf16)((v.w - mu) * inv * gg.w + bb.w);
    ((bf16x4*)hr)[lane + c * 64] = o;
  }
}

// ================= 128x128 bf16 GEMM, 2 blocks/CU (round-8 best) ==========
// 256 threads = 4 waves (2m x 2n), wave = 64x64 (4x4 frags). BK=64 -> 12
// K-tiles. LDS 64 KiB (2 bufs x 32KB) -> 2 blocks/CU (m114 overlap).
// Counted vmcnt(8): stage tile j+2 after the barrier, never drain in loop.
// T2 swizzle: XOR byte-bits 4-6 with row-bits 0-2 (involution, both sides).
// 928 TF measured (round 8) = the 128^2-structure ceiling (m103: 912).

#define SWZ(x) ((x) ^ ((((x) >> 7) & 7) << 4))

#define BAR __builtin_amdgcn_s_barrier()
#define VMC(n) asm volatile("s_waitcnt vmcnt(" #n ")" ::: "memory")
#define PRIO1 __builtin_amdgcn_s_setprio(1)
#define PRIO0 __builtin_amdgcn_s_setprio(0)

#define LDA1(base, i, ks) \
  af[i][ks] = *(const bf16x8*)((base) + SWZ((wm * 64 + (i) * 16 + llo) * 128 + (ks) * 64 + lhi * 16))
#define LDB1(base, j, ks) \
  bf[j][ks] = *(const bf16x8*)((base) + SWZ((wn * 64 + (j) * 16 + llo) * 128 + (ks) * 64 + lhi * 16))
#define RDALL(Ab, Bb) do { \
  LDA1(Ab, 0, 0); LDA1(Ab, 1, 0); LDA1(Ab, 2, 0); LDA1(Ab, 3, 0); \
  LDB1(Bb, 0, 0); LDB1(Bb, 1, 0); LDB1(Bb, 2, 0); LDB1(Bb, 3, 0); \
  LDA1(Ab, 0, 1); LDA1(Ab, 1, 1); LDA1(Ab, 2, 1); LDA1(Ab, 3, 1); \
  LDB1(Bb, 0, 1); LDB1(Bb, 1, 1); LDB1(Bb, 2, 1); LDB1(Bb, 3, 1); } while (0)

#define MF1(m, n, ks) \
  acc[m][n] = __builtin_amdgcn_mfma_f32_16x16x32_bf16(af[m][ks], bf[n][ks], acc[m][n], 0, 0, 0)
#define MFALL do { PRIO1; \
  MF1(0,0,0); MF1(0,1,0); MF1(0,2,0); MF1(0,3,0); \
  MF1(1,0,0); MF1(1,1,0); MF1(1,2,0); MF1(1,3,0); \
  MF1(2,0,0); MF1(2,1,0); MF1(2,2,0); MF1(2,3,0); \
  MF1(3,0,0); MF1(3,1,0); MF1(3,2,0); MF1(3,3,0); \
  MF1(0,0,1); MF1(0,1,1); MF1(0,2,1); MF1(0,3,1); \
  MF1(1,0,1); MF1(1,1,1); MF1(1,2,1); MF1(1,3,1); \
  MF1(2,0,1); MF1(2,1,1); MF1(2,2,1); MF1(2,3,1); \
  MF1(3,0,1); MF1(3,1,1); MF1(3,2,1); MF1(3,3,1); \
  PRIO0; } while (0)

#define STA2(b, q, t) gl_lds16(A + srcA[q] + (t) * 64, &As_[b][(q) * 2048 + wave * 512])
#define STB2(b, q, t) gl_lds16(Bt + srcB[q] + (t) * 64, &Bs_[b][(q) * 2048 + wave * 512])
#define STAGE(b, t) do { \
  STA2(b, 0, t); STA2(b, 1, t); STA2(b, 2, t); STA2(b, 3, t); \
  STB2(b, 0, t); STB2(b, 1, t); STB2(b, 2, t); STB2(b, 3, t); } while (0)

template <bool OUT_BF16>
__global__ __launch_bounds__(256, 2) void gemm128(const bf16* __restrict__ A,
                                                  const bf16* __restrict__ Bt,
                                                  void* __restrict__ Cv,
                                                  int Nn, int NBN) {
  __shared__ __align__(16) bf16 As_[2][8192];   // 16KB per buf
  __shared__ __align__(16) bf16 Bs_[2][8192];
  const int tid = threadIdx.x;
  const int wave = tid >> 6, lane = tid & 63;
  const int llo = lane & 15, lhi = lane >> 4;
  const int wm = wave >> 1, wn = wave & 1;

  const int nwg = gridDim.x, bid = blockIdx.x;
  const int wg = (bid & 7) * (nwg >> 3) + (bid >> 3);
  const int rb = wg / NBN, cb = wg - rb * NBN;
  const int brow = rb * 128, bcol = cb * 128;

  uint32_t srcA[4], srcB[4];
  #pragma unroll
  for (int q = 0; q < 4; ++q) {
    int d = q * 4096 + tid * 16;
    int a = SWZ(d);
    int r = a >> 7, c = (a & 127) >> 1;
    srcA[q] = (uint32_t)(brow + r) * GK + c;
    srcB[q] = (uint32_t)(bcol + r) * GK + c;
  }

  f32x4 acc[4][4];
  #pragma unroll
  for (int m = 0; m < 4; ++m)
    #pragma unroll
    for (int n = 0; n < 4; ++n) acc[m][n] = (f32x4){0.f, 0.f, 0.f, 0.f};

  bf16x8 af[4][2], bf[4][2];
  const char* As0 = (const char*)&As_[0][0];
  const char* As1 = (const char*)&As_[1][0];
  const char* Bs0 = (const char*)&Bs_[0][0];
  const char* Bs1 = (const char*)&Bs_[1][0];

  STAGE(0, 0);
  STAGE(1, 1);
  VMC(8);
  BAR;

  #pragma unroll
  for (int j = 0; j < 5; ++j) {
    RDALL(As0, Bs0);
    MFALL;
    BAR;
    STAGE(0, 2 * j + 2);
    VMC(8);
    BAR;
    RDALL(As1, Bs1);
    MFALL;
    BAR;
    STAGE(1, 2 * j + 3);
    VMC(8);
    BAR;
  }
  RDALL(As0, Bs0);
  MFALL;
  BAR;
  VMC(0);
  BAR;
  RDALL(As1, Bs1);
  MFALL;

  #pragma unroll
  for (int m = 0; m < 4; ++m) {
    #pragma unroll
    for (int n = 0; n < 4; ++n) {
      int row = brow + wm * 64 + m * 16 + lhi * 4;
      int col = bcol + wn * 64 + n * 16 + llo;
      #pragma unroll
      for (int r2 = 0; r2 < 4; ++r2) {
        if (OUT_BF16)
          ((bf16*)Cv)[(size_t)(row + r2) * Nn + col] = (bf16)acc[m][n][r2];
        else
          ((float*)Cv)[(size_t)(row + r2) * Nn + col] = acc[m][n][r2];
      }
    }
  }
}

// ---------------- 3a: kv partial sums, k-norm computed inline ----------------
__global__ __launch_bounds__(256) void kv_partial(const bf16* __restrict__ qkv,
                                                  float* __restrict__ kvp) {
  __shared__ float sm[4][768];
  int b = blockIdx.x >> 5, chunk = blockIdx.x & 31;
  int wave = threadIdx.x >> 6, lane = threadIdx.x & 63;
  const bf16* base = qkv + ((size_t)(b * 4096 + chunk * 128 + wave * 32)) * 2304;
  float acc[3][4] = {};
  for (int i = 0; i < 32; ++i) {
    const bf16* kr = base + (size_t)i * 2304 + 768;
    const bf16* vr = kr + 768;
    bf16x4 k4[3], v4[3];
    #pragma unroll
    for (int c = 0; c < 3; ++c) {
      k4[c] = *(const bf16x4*)(kr + c * 256 + lane * 4);
      v4[c] = *(const bf16x4*)(vr + c * 256 + lane * 4);
    }
    float ssk = 0.f;
    #pragma unroll
    for (int c = 0; c < 3; ++c)
      #pragma unroll
      for (int j = 0; j < 4; ++j) { float kf = (float)k4[c][j]; ssk += kf * kf; }
    #pragma unroll
    for (int off = 32; off > 0; off >>= 1) ssk += __shfl_xor(ssk, off, 64);
    float wi = 1.0f / fmaxf(sqrtf(ssk), NORM_EPS);
    #pragma unroll
    for (int c = 0; c < 3; ++c)
      #pragma unroll
      for (int j = 0; j < 4; ++j)
        acc[c][j] += (float)k4[c][j] * (float)v4[c][j] * wi;
  }
  #pragma unroll
  for (int c = 0; c < 3; ++c)
    #pragma unroll
    for (int j = 0; j < 4; ++j)
      sm[wave][c * 256 + lane * 4 + j] = acc[c][j];
  __syncthreads();
  int t = threadIdx.x;
  #pragma unroll
  for (int c = 0; c < 3; ++c) {
    int e = c * 256 + t;
    kvp[(size_t)blockIdx.x * 768 + e] = sm[0][e] + sm[1][e] + sm[2][e] + sm[3][e];
  }
}

// ---------------- 3b: reduce 32 partials -> kv[8][768] ----------------
__global__ __launch_bounds__(256) void kv_reduce(const float* __restrict__ kvp,
                                                 float* __restrict__ kv) {
  int i = blockIdx.x * 256 + threadIdx.x;
  int b = i / 768, e = i - b * 768;
  float s = 0.f;
  #pragma unroll
  for (int c = 0; c < 32; ++c) s += kvp[(size_t)(b * 32 + c) * 768 + e];
  kv[i] = s;
}

// ---------------- 4: attn+LN, wave-per-row (q-norm inline) ----------------
__global__ __launch_bounds__(256) void attn_ln_kernel(const bf16* __restrict__ qkv,
                                                      const float* __restrict__ kv,
                                                      const float* __restrict__ g,
                                                      const float* __restrict__ b,
                                                      bf16* __restrict__ a) {
  int wave = threadIdx.x >> 6, lane = threadIdx.x & 63;
  int row = blockIdx.x * 4 + wave;
  int bt = row >> 12;
  const bf16* qr = qkv + (size_t)row * 2304;
  bf16x4 q4[3];
  float qf[12];
  float sq = 0.f;
  #pragma unroll
  for (int c = 0; c < 3; ++c) {
    q4[c] = ((const bf16x4*)qr)[lane + c * 64];
    #pragma unroll
    for (int j = 0; j < 4; ++j) {
      float f = (float)q4[c][j];
      qf[c * 4 + j] = f;
      sq += f * f;
    }
  }
  #pragma unroll
  for (int o = 32; o > 0; o >>= 1) sq += __shfl_xor(sq, o, 64);
  float iq = 1.0f / fmaxf(sqrtf(sq), NORM_EPS);
  const float4* kvr = (const float4*)(kv + bt * 768);
  float av[12];
  float s = 0.f, ss = 0.f;
  #pragma unroll
  for (int c = 0; c < 3; ++c) {
    float4 kv4 = kvr[lane + c * 64];
    av[c * 4 + 0] = qf[c * 4 + 0] * iq * kv4.x;
    av[c * 4 + 1] = qf[c * 4 + 1] * iq * kv4.y;
    av[c * 4 + 2] = qf[c * 4 + 2] * iq * kv4.z;
    av[c * 4 + 3] = qf[c * 4 + 3] * iq * kv4.w;
    #pragma unroll
    for (int j = 0; j < 4; ++j) { s += av[c * 4 + j]; ss += av[c * 4 + j] * av[c * 4 + j]; }
  }
  #pragma unroll
  for (int o = 32; o > 0; o >>= 1) {
    s  += __shfl_xor(s, o, 64);
    ss += __shfl_xor(ss, o, 64);
  }
  float mu  = s * (1.0f / 768.0f);
  float inv = rsqrtf(ss * (1.0f / 768.0f) - mu * mu + LN_EPS);
  bf16* ar = a + (size_t)row * 768;
  #pragma unroll
  for (int c = 0; c < 3; ++c) {
    float4 gg = ((const float4*)g)[lane + c * 64];
    float4 bb = ((const float4*)b)[lane + c * 64];
    bf16x4 o;
    o[0] = (bf16)((av[c * 4 + 0] - mu) * inv * gg.x + bb.x);
    o[1] = (bf16)((av[c * 4 + 1] - mu) * inv * gg.y + bb.y);
    o[2] = (bf16)((av[c * 4 + 2] - mu) * inv * gg.z + bb.z);
    o[3] = (bf16)((av[c * 4 + 3] - mu) * inv * gg.w + bb.w);
    ((bf16x4*)ar)[lane + c * 64] = o;
  }
}

// ---------------- launcher ----------------
extern "C" void kernel_launch(void* const* d_in, const int* in_sizes, int n_in,
                              void* d_out, int out_size, void* d_ws, size_t ws_size,
                              hipStream_t stream) {
  const float* x      = (const float*)d_in[0];
  const float* w_qkv  = (const float*)d_in[1];
  const float* w_proj = (const float*)d_in[2];
  const float* g_in   = (const float*)d_in[3];
  const float* b_in   = (const float*)d_in[4];
  const float* g_out  = (const float*)d_in[5];
  const float* b_out  = (const float*)d_in[6];

  char* ws = (char*)d_ws;
  bf16*  wqkvt  = (bf16*)(ws);                              // [2304][768] bf16
  bf16*  wprojt = (bf16*)(ws + 3538944);                    // [768][768]  bf16
  bf16*  h      = (bf16*)(ws + 4718592);                    // [32768][768] bf16 (reused as 'a')
  bf16*  qkv    = (bf16*)(ws + 55050240);                   // [32768][2304] bf16
  float* kvp    = (float*)(ws + 206045184);                 // [8*32][768]
  float* kv     = (float*)(ws + 206831616);                 // [8][768]

  transpose_cvt<<<dim3(2304 / 32, 768 / 32), 256, 0, stream>>>(w_qkv, wqkvt, 768, 2304);
  transpose_cvt<<<dim3(768 / 32, 768 / 32), 256, 0, stream>>>(w_proj, wprojt, 768, 768);
  ln_in_kernel<<<8192, 256, 0, stream>>>(x, g_in, b_in, h);
  gemm128<true><<<256 * 18, 256, 0, stream>>>(h, wqkvt, (void*)qkv, 2304, 18);
  kv_partial<<<256, 256, 0, stream>>>(qkv, kvp);
  kv_reduce<<<24, 256, 0, stream>>>(kvp, kv);
  attn_ln_kernel<<<8192, 256, 0, stream>>>(qkv, kv, g_out, b_out, h);
  gemm128<false><<<256 * 6, 256, 0, stream>>>(h, wprojt, d_out, 768, 6);
}

// Round 12
// 248.427 us; speedup vs baseline: 1.1242x; 1.0043x over previous
//
#include <hip/hip_runtime.h>
#include <hip/hip_bf16.h>
#include <cstdint>

typedef __bf16 bf16;
typedef __bf16 bf16x4 __attribute__((ext_vector_type(4)));
typedef __bf16 bf16x8 __attribute__((ext_vector_type(8)));
typedef float f32x4 __attribute__((ext_vector_type(4)));

#define GK 768   // inner K for both GEMMs
#define LN_EPS 1e-5f
#define NORM_EPS 1e-12f

// ---------------- async global->LDS helper ----------------
__device__ __forceinline__ void gl_lds16(const void* g, void* l) {
  __builtin_amdgcn_global_load_lds(
      (__attribute__((address_space(1))) uint32_t*)(uintptr_t)g,
      (__attribute__((address_space(3))) uint32_t*)(uintptr_t)l,
      16, 0, 0);
}

// ---------------- 0: merged tiled transpose + fp32->bf16 (both weights) -----
// blocks [0,1728): w_qkv [768][2304] -> wqt [2304][768]
// blocks [1728,2304): w_proj [768][768] -> wpt [768][768]
__global__ __launch_bounds__(256) void transpose_cvt2(const float* __restrict__ wq,
                                                      const float* __restrict__ wp,
                                                      bf16* __restrict__ wqt,
                                                      bf16* __restrict__ wpt) {
  __shared__ float tile[32][33];
  int bid = blockIdx.x;
  const float* w; bf16* wt; int Ncols, bx, by;
  if (bid < 1728) { w = wq; wt = wqt; Ncols = 2304; bx = bid % 72; by = bid / 72; }
  else { int b2 = bid - 1728; w = wp; wt = wpt; Ncols = 768; bx = b2 % 24; by = b2 / 24; }
  int tx = threadIdx.x & 31, ty = threadIdx.x >> 5;
  int c0 = bx * 32, r0 = by * 32;
  #pragma unroll
  for (int i = 0; i < 32; i += 8)
    tile[ty + i][tx] = w[(size_t)(r0 + ty + i) * Ncols + (c0 + tx)];
  __syncthreads();
  #pragma unroll
  for (int i = 0; i < 32; i += 8)
    wt[(size_t)(c0 + ty + i) * 768 + (r0 + tx)] = (bf16)tile[tx][ty + i];
}

// ---------------- 1: input LayerNorm -> bf16, wave-per-row ----------
__global__ __launch_bounds__(256) void ln_in_kernel(const float* __restrict__ x,
                                                    const float* __restrict__ g,
                                                    const float* __restrict__ b,
                                                    bf16* __restrict__ h) {
  int wave = threadIdx.x >> 6, lane = threadIdx.x & 63;
  int row = blockIdx.x * 4 + wave;
  const float* xr = x + (size_t)row * 768;
  float4 v0 = ((const float4*)xr)[lane];
  float4 v1 = ((const float4*)xr)[lane + 64];
  float4 v2 = ((const float4*)xr)[lane + 128];
  float s  = v0.x + v0.y + v0.z + v0.w + v1.x + v1.y + v1.z + v1.w
           + v2.x + v2.y + v2.z + v2.w;
  float ss = v0.x*v0.x + v0.y*v0.y + v0.z*v0.z + v0.w*v0.w
           + v1.x*v1.x + v1.y*v1.y + v1.z*v1.z + v1.w*v1.w
           + v2.x*v2.x + v2.y*v2.y + v2.z*v2.z + v2.w*v2.w;
  #pragma unroll
  for (int o = 32; o > 0; o >>= 1) {
    s  += __shfl_xor(s, o, 64);
    ss += __shfl_xor(ss, o, 64);
  }
  float mu  = s * (1.0f / 768.0f);
  float inv = rsqrtf(ss * (1.0f / 768.0f) - mu * mu + LN_EPS);
  bf16* hr = h + (size_t)row * 768;
  #pragma unroll
  for (int c = 0; c < 3; ++c) {
    float4 v = c == 0 ? v0 : (c == 1 ? v1 : v2);
    float4 gg = ((const float4*)g)[lane + c * 64];
    float4 bb = ((const float4*)b)[lane + c * 64];
    bf16x4 o;
    o[0] = (bf16)((v.x - mu) * inv * gg.x + bb.x);
    o[1] = (bf16)((v.y - mu) * inv * gg.y + bb.y);
    o[2] = (bf16)((v.z - mu) * inv * gg.z + bb.z);
    o[3] = (bf16)((v.w - mu) * inv * gg.w + bb.w);
    ((bf16x4*)hr)[lane + c * 64] = o;
  }
}

// ================= 128x128 bf16 GEMM, 2 blocks/CU (round-8/11 best) ========
// LDS-bandwidth-saturated at this structure (~928 TF); do not touch.

#define SWZ(x) ((x) ^ ((((x) >> 7) & 7) << 4))

#define BAR __builtin_amdgcn_s_barrier()
#define VMC(n) asm volatile("s_waitcnt vmcnt(" #n ")" ::: "memory")
#define PRIO1 __builtin_amdgcn_s_setprio(1)
#define PRIO0 __builtin_amdgcn_s_setprio(0)

#define LDA1(base, i, ks) \
  af[i][ks] = *(const bf16x8*)((base) + SWZ((wm * 64 + (i) * 16 + llo) * 128 + (ks) * 64 + lhi * 16))
#define LDB1(base, j, ks) \
  bf[j][ks] = *(const bf16x8*)((base) + SWZ((wn * 64 + (j) * 16 + llo) * 128 + (ks) * 64 + lhi * 16))
#define RDALL(Ab, Bb) do { \
  LDA1(Ab, 0, 0); LDA1(Ab, 1, 0); LDA1(Ab, 2, 0); LDA1(Ab, 3, 0); \
  LDB1(Bb, 0, 0); LDB1(Bb, 1, 0); LDB1(Bb, 2, 0); LDB1(Bb, 3, 0); \
  LDA1(Ab, 0, 1); LDA1(Ab, 1, 1); LDA1(Ab, 2, 1); LDA1(Ab, 3, 1); \
  LDB1(Bb, 0, 1); LDB1(Bb, 1, 1); LDB1(Bb, 2, 1); LDB1(Bb, 3, 1); } while (0)

#define MF1(m, n, ks) \
  acc[m][n] = __builtin_amdgcn_mfma_f32_16x16x32_bf16(af[m][ks], bf[n][ks], acc[m][n], 0, 0, 0)
#define MFALL do { PRIO1; \
  MF1(0,0,0); MF1(0,1,0); MF1(0,2,0); MF1(0,3,0); \
  MF1(1,0,0); MF1(1,1,0); MF1(1,2,0); MF1(1,3,0); \
  MF1(2,0,0); MF1(2,1,0); MF1(2,2,0); MF1(2,3,0); \
  MF1(3,0,0); MF1(3,1,0); MF1(3,2,0); MF1(3,3,0); \
  MF1(0,0,1); MF1(0,1,1); MF1(0,2,1); MF1(0,3,1); \
  MF1(1,0,1); MF1(1,1,1); MF1(1,2,1); MF1(1,3,1); \
  MF1(2,0,1); MF1(2,1,1); MF1(2,2,1); MF1(2,3,1); \
  MF1(3,0,1); MF1(3,1,1); MF1(3,2,1); MF1(3,3,1); \
  PRIO0; } while (0)

#define STA2(b, q, t) gl_lds16(A + srcA[q] + (t) * 64, &As_[b][(q) * 2048 + wave * 512])
#define STB2(b, q, t) gl_lds16(Bt + srcB[q] + (t) * 64, &Bs_[b][(q) * 2048 + wave * 512])
#define STAGE(b, t) do { \
  STA2(b, 0, t); STA2(b, 1, t); STA2(b, 2, t); STA2(b, 3, t); \
  STB2(b, 0, t); STB2(b, 1, t); STB2(b, 2, t); STB2(b, 3, t); } while (0)

template <bool OUT_BF16>
__global__ __launch_bounds__(256, 2) void gemm128(const bf16* __restrict__ A,
                                                  const bf16* __restrict__ Bt,
                                                  void* __restrict__ Cv,
                                                  int Nn, int NBN) {
  __shared__ __align__(16) bf16 As_[2][8192];
  __shared__ __align__(16) bf16 Bs_[2][8192];
  const int tid = threadIdx.x;
  const int wave = tid >> 6, lane = tid & 63;
  const int llo = lane & 15, lhi = lane >> 4;
  const int wm = wave >> 1, wn = wave & 1;

  const int nwg = gridDim.x, bid = blockIdx.x;
  const int wg = (bid & 7) * (nwg >> 3) + (bid >> 3);
  const int rb = wg / NBN, cb = wg - rb * NBN;
  const int brow = rb * 128, bcol = cb * 128;

  uint32_t srcA[4], srcB[4];
  #pragma unroll
  for (int q = 0; q < 4; ++q) {
    int d = q * 4096 + tid * 16;
    int a = SWZ(d);
    int r = a >> 7, c = (a & 127) >> 1;
    srcA[q] = (uint32_t)(brow + r) * GK + c;
    srcB[q] = (uint32_t)(bcol + r) * GK + c;
  }

  f32x4 acc[4][4];
  #pragma unroll
  for (int m = 0; m < 4; ++m)
    #pragma unroll
    for (int n = 0; n < 4; ++n) acc[m][n] = (f32x4){0.f, 0.f, 0.f, 0.f};

  bf16x8 af[4][2], bf[4][2];
  const char* As0 = (const char*)&As_[0][0];
  const char* As1 = (const char*)&As_[1][0];
  const char* Bs0 = (const char*)&Bs_[0][0];
  const char* Bs1 = (const char*)&Bs_[1][0];

  STAGE(0, 0);
  STAGE(1, 1);
  VMC(8);
  BAR;

  #pragma unroll
  for (int j = 0; j < 5; ++j) {
    RDALL(As0, Bs0);
    MFALL;
    BAR;
    STAGE(0, 2 * j + 2);
    VMC(8);
    BAR;
    RDALL(As1, Bs1);
    MFALL;
    BAR;
    STAGE(1, 2 * j + 3);
    VMC(8);
    BAR;
  }
  RDALL(As0, Bs0);
  MFALL;
  BAR;
  VMC(0);
  BAR;
  RDALL(As1, Bs1);
  MFALL;

  #pragma unroll
  for (int m = 0; m < 4; ++m) {
    #pragma unroll
    for (int n = 0; n < 4; ++n) {
      int row = brow + wm * 64 + m * 16 + lhi * 4;
      int col = bcol + wn * 64 + n * 16 + llo;
      #pragma unroll
      for (int r2 = 0; r2 < 4; ++r2) {
        if (OUT_BF16)
          ((bf16*)Cv)[(size_t)(row + r2) * Nn + col] = (bf16)acc[m][n][r2];
        else
          ((float*)Cv)[(size_t)(row + r2) * Nn + col] = acc[m][n][r2];
      }
    }
  }
}

// ---------------- 3a: kv partial sums, k-norm inline, 4 blocks/CU ----------
// grid = 8 batches * 128 chunks of 32 tokens; wave owns 8 tokens.
__global__ __launch_bounds__(256) void kv_partial(const bf16* __restrict__ qkv,
                                                  float* __restrict__ kvp) {
  __shared__ float sm[4][768];
  int b = blockIdx.x >> 7, chunk = blockIdx.x & 127;
  int wave = threadIdx.x >> 6, lane = threadIdx.x & 63;
  const bf16* base = qkv + ((size_t)(b * 4096 + chunk * 32 + wave * 8)) * 2304;
  float acc8[8] = {}, acc4[4] = {};
  #pragma unroll
  for (int i = 0; i < 8; ++i) {
    const bf16* kr = base + (size_t)i * 2304 + 768;
    const bf16* vr = kr + 768;
    bf16x8 k8 = *(const bf16x8*)(kr + lane * 8);
    bf16x4 k4 = *(const bf16x4*)(kr + 512 + lane * 4);
    bf16x8 v8 = *(const bf16x8*)(vr + lane * 8);
    bf16x4 v4 = *(const bf16x4*)(vr + 512 + lane * 4);
    float kf8[8], kf4[4];
    float ssk = 0.f;
    #pragma unroll
    for (int j = 0; j < 8; ++j) { kf8[j] = (float)k8[j]; ssk += kf8[j] * kf8[j]; }
    #pragma unroll
    for (int j = 0; j < 4; ++j) { kf4[j] = (float)k4[j]; ssk += kf4[j] * kf4[j]; }
    #pragma unroll
    for (int off = 32; off > 0; off >>= 1) ssk += __shfl_xor(ssk, off, 64);
    float wi = 1.0f / fmaxf(sqrtf(ssk), NORM_EPS);
    #pragma unroll
    for (int j = 0; j < 8; ++j) acc8[j] += kf8[j] * (float)v8[j] * wi;
    #pragma unroll
    for (int j = 0; j < 4; ++j) acc4[j] += kf4[j] * (float)v4[j] * wi;
  }
  #pragma unroll
  for (int j = 0; j < 8; ++j) sm[wave][lane * 8 + j] = acc8[j];
  #pragma unroll
  for (int j = 0; j < 4; ++j) sm[wave][512 + lane * 4 + j] = acc4[j];
  __syncthreads();
  int t = threadIdx.x;
  #pragma unroll
  for (int c = 0; c < 3; ++c) {
    int e = c * 256 + t;
    kvp[(size_t)blockIdx.x * 768 + e] = sm[0][e] + sm[1][e] + sm[2][e] + sm[3][e];
  }
}

// ---------------- 3b: reduce 128 partials -> kv[8][768] ----------------
__global__ __launch_bounds__(256) void kv_reduce(const float* __restrict__ kvp,
                                                 float* __restrict__ kv) {
  int i = blockIdx.x * 256 + threadIdx.x;   // 0..6143
  int b = i / 768, e = i - b * 768;
  float s = 0.f;
  #pragma unroll 8
  for (int c = 0; c < 128; ++c) s += kvp[(size_t)(b * 128 + c) * 768 + e];
  kv[i] = s;
}

// ---------------- 4: attn+LN, wave-per-row (q-norm inline) ----------------
__global__ __launch_bounds__(256) void attn_ln_kernel(const bf16* __restrict__ qkv,
                                                      const float* __restrict__ kv,
                                                      const float* __restrict__ g,
                                                      const float* __restrict__ b,
                                                      bf16* __restrict__ a) {
  int wave = threadIdx.x >> 6, lane = threadIdx.x & 63;
  int row = blockIdx.x * 4 + wave;
  int bt = row >> 12;
  const bf16* qr = qkv + (size_t)row * 2304;
  bf16x4 q4[3];
  float qf[12];
  float sq = 0.f;
  #pragma unroll
  for (int c = 0; c < 3; ++c) {
    q4[c] = ((const bf16x4*)qr)[lane + c * 64];
    #pragma unroll
    for (int j = 0; j < 4; ++j) {
      float f = (float)q4[c][j];
      qf[c * 4 + j] = f;
      sq += f * f;
    }
  }
  #pragma unroll
  for (int o = 32; o > 0; o >>= 1) sq += __shfl_xor(sq, o, 64);
  float iq = 1.0f / fmaxf(sqrtf(sq), NORM_EPS);
  const float4* kvr = (const float4*)(kv + bt * 768);
  float av[12];
  float s = 0.f, ss = 0.f;
  #pragma unroll
  for (int c = 0; c < 3; ++c) {
    float4 kv4 = kvr[lane + c * 64];
    av[c * 4 + 0] = qf[c * 4 + 0] * iq * kv4.x;
    av[c * 4 + 1] = qf[c * 4 + 1] * iq * kv4.y;
    av[c * 4 + 2] = qf[c * 4 + 2] * iq * kv4.z;
    av[c * 4 + 3] = qf[c * 4 + 3] * iq * kv4.w;
    #pragma unroll
    for (int j = 0; j < 4; ++j) { s += av[c * 4 + j]; ss += av[c * 4 + j] * av[c * 4 + j]; }
  }
  #pragma unroll
  for (int o = 32; o > 0; o >>= 1) {
    s  += __shfl_xor(s, o, 64);
    ss += __shfl_xor(ss, o, 64);
  }
  float mu  = s * (1.0f / 768.0f);
  float inv = rsqrtf(ss * (1.0f / 768.0f) - mu * mu + LN_EPS);
  bf16* ar = a + (size_t)row * 768;
  #pragma unroll
  for (int c = 0; c < 3; ++c) {
    float4 gg = ((const float4*)g)[lane + c * 64];
    float4 bb = ((const float4*)b)[lane + c * 64];
    bf16x4 o;
    o[0] = (bf16)((av[c * 4 + 0] - mu) * inv * gg.x + bb.x);
    o[1] = (bf16)((av[c * 4 + 1] - mu) * inv * gg.y + bb.y);
    o[2] = (bf16)((av[c * 4 + 2] - mu) * inv * gg.z + bb.z);
    o[3] = (bf16)((av[c * 4 + 3] - mu) * inv * gg.w + bb.w);
    ((bf16x4*)ar)[lane + c * 64] = o;
  }
}

// ---------------- launcher ----------------
extern "C" void kernel_launch(void* const* d_in, const int* in_sizes, int n_in,
                              void* d_out, int out_size, void* d_ws, size_t ws_size,
                              hipStream_t stream) {
  const float* x      = (const float*)d_in[0];
  const float* w_qkv  = (const float*)d_in[1];
  const float* w_proj = (const float*)d_in[2];
  const float* g_in   = (const float*)d_in[3];
  const float* b_in   = (const float*)d_in[4];
  const float* g_out  = (const float*)d_in[5];
  const float* b_out  = (const float*)d_in[6];

  char* ws = (char*)d_ws;
  bf16*  wqkvt  = (bf16*)(ws);                              // [2304][768] bf16
  bf16*  wprojt = (bf16*)(ws + 3538944);                    // [768][768]  bf16
  bf16*  h      = (bf16*)(ws + 4718592);                    // [32768][768] bf16 (reused as 'a')
  bf16*  qkv    = (bf16*)(ws + 55050240);                   // [32768][2304] bf16
  float* kvp    = (float*)(ws + 206045184);                 // [1024][768] fp32
  float* kv     = (float*)(ws + 209190912);                 // [8][768]

  transpose_cvt2<<<2304, 256, 0, stream>>>(w_qkv, w_proj, wqkvt, wprojt);
  ln_in_kernel<<<8192, 256, 0, stream>>>(x, g_in, b_in, h);
  gemm128<true><<<256 * 18, 256, 0, stream>>>(h, wqkvt, (void*)qkv, 2304, 18);
  kv_partial<<<1024, 256, 0, stream>>>(qkv, kvp);
  kv_reduce<<<24, 256, 0, stream>>>(kvp, kv);
  attn_ln_kernel<<<8192, 256, 0, stream>>>(qkv, kv, g_out, b_out, h);
  gemm128<false><<<256 * 6, 256, 0, stream>>>(h, wprojt, d_out, 768, 6);
}